// Round 6
// baseline (358.066 us; speedup 1.0000x reference)
//
#include <hip/hip_runtime.h>

#define B_ 512
#define L_ 512
#define N_ 128
#define TM 256          // boundary: fwd produces alpha_255, bwd produces beta_255
#define C_BIAS 3.0f

typedef _Float16 h2_t __attribute__((ext_vector_type(2)));

__device__ __forceinline__ float dot2f(h2_t a, h2_t b, float c) {
#if __has_builtin(__builtin_amdgcn_fdot2)
    return __builtin_amdgcn_fdot2(a, b, c, false);
#else
    return c + (float)a[0] * (float)b[0] + (float)a[1] * (float)b[1];
#endif
}

// ---- full-rate VALU wave-64 reductions via DPP ----
#define DPP_STEP_MAX(v, ctrl)                                                   \
    {                                                                           \
        int _t = __builtin_amdgcn_update_dpp(__float_as_int(v),                 \
                    __float_as_int(v), ctrl, 0xf, 0xf, false);                  \
        v = fmaxf(v, __int_as_float(_t));                                       \
    }
#define DPP_STEP_ADD(v, ctrl)                                                   \
    {                                                                           \
        int _t = __builtin_amdgcn_update_dpp(__float_as_int(v),                 \
                    __float_as_int(v), ctrl, 0xf, 0xf, false);                  \
        v = v + __int_as_float(_t);                                             \
    }

__device__ __forceinline__ float wave_max(float v) {
    DPP_STEP_MAX(v, 0xB1);   // quad_perm [1,0,3,2]
    DPP_STEP_MAX(v, 0x4E);   // quad_perm [2,3,0,1]
    DPP_STEP_MAX(v, 0x141);  // row_half_mirror
    DPP_STEP_MAX(v, 0x140);  // row_mirror
    DPP_STEP_MAX(v, 0x142);  // row_bcast15
    DPP_STEP_MAX(v, 0x143);  // row_bcast31
    return __int_as_float(__builtin_amdgcn_readlane(__float_as_int(v), 63));
}
__device__ __forceinline__ float wave_sum(float v) {
    DPP_STEP_ADD(v, 0xB1);
    DPP_STEP_ADD(v, 0x4E);
    DPP_STEP_ADD(v, 0x141);
    DPP_STEP_ADD(v, 0x140);
    DPP_STEP_ADD(v, 0x142);
    DPP_STEP_ADD(v, 0x143);
    return __int_as_float(__builtin_amdgcn_readlane(__float_as_int(v), 63));
}

// LDS-only barrier: waits lgkmcnt(0) (LDS writes visible) but does NOT drain
// vmcnt -> global prefetch loads stay in flight across the barrier.
__device__ __forceinline__ void lds_barrier() {
    asm volatile("s_waitcnt lgkmcnt(0)\n\ts_barrier" ::: "memory");
}

// ---------------------------------------------------------------------------
// norm_kernel: 1024 blocks x 128 threads (2 waves) -> 2048 waves = 2/SIMD.
// blockIdx: b = x>>1 ; bw = x&1 (0=fwd scan t=0..255, 1=bwd scan t=511..255).
// Lane owns exactly ONE state (tid). Fwd: ET column fragment (64 h2) in regs;
// bwd: ET row fragment. E/F vector (128 f16) + per-step max exchanged through
// parity double-buffered LDS; one raw LDS-barrier per step (no vmcnt drain).
// Max is lag-1 (E_t normalized by max ns_{t-1}) — validated absmax 0.0 in r4/5.
// ---------------------------------------------------------------------------
__global__ __launch_bounds__(128, 2) void norm_kernel(
    const float* __restrict__ em, const int* __restrict__ tg,
    const float* __restrict__ mask, const float* __restrict__ st,
    const float* __restrict__ trans,
    float* __restrict__ alpha, float* __restrict__ beta,
    float* __restrict__ pathf, float* __restrict__ pathb)
{
    __shared__ __align__(16) h2_t Ehb[2][64];   // E/F vector, parity buffered
    __shared__ __align__(8)  float pm2[2][2];   // per-wave max, parity buffered
    __shared__ float Mlds[TM];                  // mask half-row
    __shared__ float pred[2];

    const int tid = threadIdx.x;     // 0..127 == state index
    const int w   = tid >> 6;
    const int l   = tid & 63;
    const int b   = blockIdx.x >> 1;
    const int bw  = blockIdx.x & 1;
    const size_t base = (size_t)b * L_ * N_;
    const int bL = b * L_;

    if (bw == 0) {
        // ================= FORWARD =================
        float pacc = 0.f;
        for (int t = 1 + tid; t < TM; t += 128) {
            int cur  = tg[bL + t];
            int prev = tg[bL + t - 1];
            pacc += mask[bL + t] * (trans[prev * N_ + cur] + em[base + (size_t)t * N_ + cur]);
        }
        pacc = wave_sum(pacc);
        if (l == 0) pred[w] = pacc;

        Mlds[tid]       = mask[bL + tid];
        Mlds[tid + 128] = mask[bL + tid + 128];

        // ET column fragment: et[k] = (exp T[2k][tid], exp T[2k+1][tid])
        h2_t et[64];
#pragma unroll
        for (int k = 0; k < 64; ++k) {
            float f0 = __expf(trans[(2 * k    ) * N_ + tid]);
            float f1 = __expf(trans[(2 * k + 1) * N_ + tid]);
            h2_t e; e[0] = (_Float16)f0; e[1] = (_Float16)f1;
            et[k] = e;
        }

        // init: ns_0, exact max, E_0 -> buffer 0
        float ns = st[tid] + em[base + tid];
        {
            float mxw = wave_max(ns);
            if (l == 0) pm2[0][w] = mxw;
        }
        __syncthreads();
        if (tid == 0) {
            int t0 = tg[bL];
            pathf[b] = pred[0] + pred[1] + st[t0] + em[base + t0];
        }
        float2 pmv0 = *(const float2*)pm2[0];
        float Mstar = fmaxf(pmv0.x, pmv0.y);
        ((_Float16*)Ehb[0])[tid] = (_Float16)__expf(ns - Mstar - C_BIAS);
        float Mcarry = Mstar;

        // emission prefetch pipe (1 float/lane), distance 4
        float pipe0 = em[base + (size_t)1 * N_ + tid];
        float pipe1 = em[base + (size_t)2 * N_ + tid];
        float pipe2 = em[base + (size_t)3 * N_ + tid];
        float pipe3 = em[base + (size_t)4 * N_ + tid];

        auto step = [&](int t, float& slot, int rd, int wr) {
            lds_barrier();                       // LDS-only; prefetch rides across
            float emv = slot;
            int tpf = t + 4; if (tpf > TM - 1) tpf = TM - 1;
            slot = em[base + (size_t)tpf * N_ + tid];

            float2 pmv = *(const float2*)pm2[rd];
            float Ms = fmaxf(pmv.x, pmv.y);      // max(ns_{t-1})
            float mk = Mlds[t];

            const float4* E4 = (const float4*)Ehb[rd];
            float a0 = 0.f, a1 = 0.f, a2 = 0.f, a3 = 0.f;
            float a4 = 0.f, a5 = 0.f, a6 = 0.f, a7 = 0.f;
#pragma unroll
            for (int r = 0; r < 8; ++r) {
                float4 b0v = E4[2 * r];
                float4 b1v = E4[2 * r + 1];
                const h2_t* e0 = (const h2_t*)&b0v;
                const h2_t* e1 = (const h2_t*)&b1v;
                a0 = dot2f(e0[0], et[8 * r + 0], a0);
                a1 = dot2f(e0[1], et[8 * r + 1], a1);
                a2 = dot2f(e0[2], et[8 * r + 2], a2);
                a3 = dot2f(e0[3], et[8 * r + 3], a3);
                a4 = dot2f(e1[0], et[8 * r + 4], a4);
                a5 = dot2f(e1[1], et[8 * r + 5], a5);
                a6 = dot2f(e1[2], et[8 * r + 6], a6);
                a7 = dot2f(e1[3], et[8 * r + 7], a7);
            }
            float s = ((a0 + a1) + (a2 + a3)) + ((a4 + a5) + (a6 + a7));

            float nxt = __logf(s) + Mcarry + C_BIAS + emv;
            ns = mk * nxt + (1.f - mk) * ns;

            float mxw = wave_max(ns);
            if (l == 0) pm2[wr][w] = mxw;
            ((_Float16*)Ehb[wr])[tid] = (_Float16)__expf(ns - Ms - C_BIAS);
            Mcarry = Ms;
        };

        for (int tt = 1; tt + 3 < TM; tt += 4) {
            step(tt    , pipe0, 0, 1);
            step(tt + 1, pipe1, 1, 0);
            step(tt + 2, pipe2, 0, 1);
            step(tt + 3, pipe3, 1, 0);
        }
        step(TM - 3, pipe0, 0, 1);
        step(TM - 2, pipe1, 1, 0);
        step(TM - 1, pipe2, 0, 1);

        alpha[b * N_ + tid] = ns;
    } else {
        // ================= BACKWARD =================
        float pacc = 0.f;
        for (int t = TM + tid; t < L_; t += 128) {
            int cur  = tg[bL + t];
            int prev = tg[bL + t - 1];
            pacc += mask[bL + t] * (trans[prev * N_ + cur] + em[base + (size_t)t * N_ + cur]);
        }
        pacc = wave_sum(pacc);
        if (l == 0) pred[w] = pacc;

        Mlds[tid]       = mask[bL + TM + tid];
        Mlds[tid + 128] = mask[bL + TM + tid + 128];

        // ET row fragment: er[k] = (exp T[tid][2k], exp T[tid][2k+1])
        h2_t er[64];
#pragma unroll
        for (int k = 0; k < 64; ++k) {
            float2 q = *(const float2*)(trans + tid * N_ + 2 * k);
            h2_t e; e[0] = (_Float16)__expf(q.x); e[1] = (_Float16)__expf(q.y);
            er[k] = e;
        }

        // init at t=511: beta=0, v = em_511
        float bsc = 0.f;
        float v = em[base + (size_t)(L_ - 1) * N_ + tid];
        {
            float mxw = wave_max(v);
            if (l == 0) pm2[0][w] = mxw;
        }
        __syncthreads();
        if (tid == 0) pathb[b] = pred[0] + pred[1];
        float2 pmv0 = *(const float2*)pm2[0];
        float Mstar = fmaxf(pmv0.x, pmv0.y);
        ((_Float16*)Ehb[0])[tid] = (_Float16)__expf(v - Mstar - C_BIAS);
        float Mcarry = Mstar;

        float pipe0 = em[base + (size_t)510 * N_ + tid];
        float pipe1 = em[base + (size_t)509 * N_ + tid];
        float pipe2 = em[base + (size_t)508 * N_ + tid];
        float pipe3 = em[base + (size_t)507 * N_ + tid];

        auto step = [&](int t, float& slot, int rd, int wr) {
            lds_barrier();
            float emv = slot;                    // em_t
            int tpf = t - 4; if (tpf < TM - 1) tpf = TM - 1;
            slot = em[base + (size_t)tpf * N_ + tid];

            float2 pmv = *(const float2*)pm2[rd];
            float Ms = fmaxf(pmv.x, pmv.y);      // max(v_{t+1})
            float mk = Mlds[t + 1 - TM];

            const float4* F4 = (const float4*)Ehb[rd];
            float a0 = 0.f, a1 = 0.f, a2 = 0.f, a3 = 0.f;
            float a4 = 0.f, a5 = 0.f, a6 = 0.f, a7 = 0.f;
#pragma unroll
            for (int r = 0; r < 8; ++r) {
                float4 b0v = F4[2 * r];
                float4 b1v = F4[2 * r + 1];
                const h2_t* f0 = (const h2_t*)&b0v;
                const h2_t* f1 = (const h2_t*)&b1v;
                a0 = dot2f(f0[0], er[8 * r + 0], a0);
                a1 = dot2f(f0[1], er[8 * r + 1], a1);
                a2 = dot2f(f0[2], er[8 * r + 2], a2);
                a3 = dot2f(f0[3], er[8 * r + 3], a3);
                a4 = dot2f(f1[0], er[8 * r + 4], a4);
                a5 = dot2f(f1[1], er[8 * r + 5], a5);
                a6 = dot2f(f1[2], er[8 * r + 6], a6);
                a7 = dot2f(f1[3], er[8 * r + 7], a7);
            }
            float s = ((a0 + a1) + (a2 + a3)) + ((a4 + a5) + (a6 + a7));

            float upd = __logf(s) + Mcarry + C_BIAS;
            bsc = mk * upd + (1.f - mk) * bsc;
            v = bsc + emv;

            float mxw = wave_max(v);
            if (l == 0) pm2[wr][w] = mxw;
            ((_Float16*)Ehb[wr])[tid] = (_Float16)__expf(v - Ms - C_BIAS);
            Mcarry = Ms;
        };

        for (int tt = 510; tt >= 258; tt -= 4) {   // t = 510..255, 256 steps
            step(tt    , pipe0, 0, 1);
            step(tt - 1, pipe1, 1, 0);
            step(tt - 2, pipe2, 0, 1);
            step(tt - 3, pipe3, 1, 0);
        }

        beta[b * N_ + tid] = bsc;
    }
}

// ---------------------------------------------------------------------------
__global__ __launch_bounds__(1024) void combine_kernel(
    const float* __restrict__ alpha, const float* __restrict__ beta,
    const float* __restrict__ pathf, const float* __restrict__ pathb,
    float* __restrict__ out)
{
    __shared__ float part[16];
    const int tid = threadIdx.x;
    const int w = tid >> 6;
    const int l = tid & 63;
    float acc = 0.f;
    for (int k = 0; k < 32; ++k) {
        int b = w * 32 + k;
        float2 av = *(const float2*)(alpha + b * N_ + 2 * l);
        float2 bv = *(const float2*)(beta  + b * N_ + 2 * l);
        float v0 = av.x + bv.x;
        float v1 = av.y + bv.y;
        float m = wave_max(fmaxf(v0, v1));
        float s = wave_sum(__expf(v0 - m) + __expf(v1 - m));
        if (l == 0) acc += m + __logf(s) - pathf[b] - pathb[b];
    }
    if (l == 0) part[w] = acc;
    __syncthreads();
    if (tid == 0) {
        float t = 0.f;
#pragma unroll
        for (int i = 0; i < 16; ++i) t += part[i];
        out[0] = t / (float)B_;
    }
}

// ---------------------------------------------------------------------------
extern "C" void kernel_launch(void* const* d_in, const int* in_sizes, int n_in,
                              void* d_out, int out_size, void* d_ws, size_t ws_size,
                              hipStream_t stream) {
    const float* emission    = (const float*)d_in[0];
    const int*   target      = (const int*)  d_in[1];
    const float* mask        = (const float*)d_in[2];
    const float* start_trans = (const float*)d_in[3];
    const float* trans       = (const float*)d_in[4];
    float* out = (float*)d_out;

    float* ws_f  = (float*)d_ws;
    float* alpha = ws_f;                    // 512*128
    float* beta  = ws_f + B_ * N_;          // 512*128
    float* pathf = ws_f + 2 * B_ * N_;      // 512
    float* pathb = ws_f + 2 * B_ * N_ + B_; // 512

    norm_kernel   <<<2 * B_, 128, 0, stream>>>(emission, target, mask, start_trans,
                                               trans, alpha, beta, pathf, pathb);
    combine_kernel<<<1, 1024, 0, stream>>>(alpha, beta, pathf, pathb, out);
}